// Round 8
// baseline (1574.164 us; speedup 1.0000x reference)
//
#include <hip/hip_runtime.h>
#include <math.h>

#define BSZ 16
#define NPTS 2048
#define NG 128
#define GS 32
#define NBRK 38

typedef _Float16 f16;
typedef _Float16 f16x8 __attribute__((ext_vector_type(8)));
typedef float f32x4 __attribute__((ext_vector_type(4)));

// ---------- helpers ----------
__device__ __forceinline__ unsigned fkey(float x) {
    unsigned u = __float_as_uint(x);
    return (u >> 31) ? ~u : (u | 0x80000000u);
}
__device__ __forceinline__ float fkey_inv(unsigned k) {
    unsigned u = (k >> 31) ? (k ^ 0x80000000u) : ~k;
    return __uint_as_float(u);
}

// 64-lane min via DPP (no LDS/DS pipe): row_shr 1/2/4/8 prefix + row_bcast 15/31,
// then readlane 63 broadcasts the full-wave min.
__device__ __forceinline__ unsigned wave_min_u32(unsigned v) {
    unsigned t;
    t = (unsigned)__builtin_amdgcn_update_dpp(-1, (int)v, 0x111, 0xF, 0xF, false);
    v = v < t ? v : t;
    t = (unsigned)__builtin_amdgcn_update_dpp(-1, (int)v, 0x112, 0xF, 0xF, false);
    v = v < t ? v : t;
    t = (unsigned)__builtin_amdgcn_update_dpp(-1, (int)v, 0x114, 0xF, 0xF, false);
    v = v < t ? v : t;
    t = (unsigned)__builtin_amdgcn_update_dpp(-1, (int)v, 0x118, 0xF, 0xF, false);
    v = v < t ? v : t;
    t = (unsigned)__builtin_amdgcn_update_dpp(-1, (int)v, 0x142, 0xA, 0xF, false);
    v = v < t ? v : t;
    t = (unsigned)__builtin_amdgcn_update_dpp(-1, (int)v, 0x143, 0xC, 0xF, false);
    v = v < t ? v : t;
    return (unsigned)__builtin_amdgcn_readlane((int)v, 63);
}

// ---------- FPS v3: ONE wave per batch, all points in registers, no barriers ----------
// 32 points per lane; exact lex argmax (max dist, tie -> lowest index) via 6-step
// shuffle butterfly that carries the winner's coordinates, so there is no dependent
// global load and no LDS/barrier in the 128-iteration chain.
__global__ void fps_kernel_v3(const float* __restrict__ pts, float* __restrict__ center) {
    int b = blockIdx.x;
    int lane = threadIdx.x;              // 64 threads
    const float* P = pts + (size_t)b * NPTS * 3;
    float px[32], py[32], pz[32], mind[32];
#pragma unroll
    for (int m = 0; m < 32; ++m) {
        int j = lane + (m << 6);
        px[m] = P[j * 3 + 0]; py[m] = P[j * 3 + 1]; pz[m] = P[j * 3 + 2];
        mind[m] = 1e10f;
    }
    float fx = P[0], fy = P[1], fz = P[2];   // far = index 0 initially
    for (int g = 0; g < NG; ++g) {
        if (lane == 0) {
            center[((size_t)b * NG + g) * 3 + 0] = fx;
            center[((size_t)b * NG + g) * 3 + 1] = fy;
            center[((size_t)b * NG + g) * 3 + 2] = fz;
        }
        float best = -1.0f; int bi = 0;
        float bx = 0.f, by = 0.f, bz = 0.f;
#pragma unroll
        for (int m = 0; m < 32; ++m) {
            float dx = px[m] - fx, dy = py[m] - fy, dz = pz[m] - fz;
            float d = dx * dx + dy * dy + dz * dz;
            float md = fminf(mind[m], d);
            mind[m] = md;
            if (md > best) {                 // ascending m: first max kept (lowest idx)
                best = md; bi = lane + (m << 6);
                bx = px[m]; by = py[m]; bz = pz[m];
            }
        }
#pragma unroll
        for (int s = 1; s < 64; s <<= 1) {
            float ov = __shfl_xor(best, s, 64);
            int   oi = __shfl_xor(bi, s, 64);
            float ox = __shfl_xor(bx, s, 64);
            float oy = __shfl_xor(by, s, 64);
            float oz = __shfl_xor(bz, s, 64);
            if (ov > best || (ov == best && oi < bi)) {
                best = ov; bi = oi; bx = ox; by = oy; bz = oz;
            }
        }
        fx = bx; fy = by; fz = bz;
    }
}

// ---------- KNN v8: per-query adaptive 21-bit quantization + DPP wave-min ----------
// key = (qd << 11) | idx with qd = (d - dmin_q) * (2^21-1)/(dmax_q - dmin_q):
// full 21-bit resolution across each query's own distance spread (quantum ~5e-7
// relative), so u32 order == stable top_k order for all practical inputs.
// Per-lane top-4 key cache + watermark refill (rare); wave per query; no barriers.
__global__ void knn_kernel_v8(const float* __restrict__ Q, int q_bstride, int q_off, int nq,
                              const float* __restrict__ DB, int k,
                              int* __restrict__ out, int nbatch) {
    const unsigned KINF = 0xFFFFFFFFu;
    int wave = threadIdx.x >> 6, lane = threadIdx.x & 63;
    int qidx = blockIdx.x * 4 + wave;
    if (qidx >= nbatch * nq) return;     // wave-uniform
    int b = qidx / nq, qi = qidx % nq;
    const float* q = Q + ((size_t)b * q_bstride + q_off + qi) * 3;
    float qx = q[0], qy = q[1], qz = q[2];
    float qq = qx * qx + qy * qy + qz * qz;
    const float* db = DB + (size_t)b * NPTS * 3;

    float d[32];
    float dmn = 3e38f, dmx = -3e38f;
#pragma unroll
    for (int m = 0; m < 32; ++m) {
        int j = lane + (m << 6);
        float bx = db[j * 3 + 0], by = db[j * 3 + 1], bz = db[j * 3 + 2];
        float dv = qq + bx * bx + by * by + bz * bz - 2.0f * (qx * bx + qy * by + qz * bz);
        d[m] = dv;
        dmn = fminf(dmn, dv);
        dmx = fmaxf(dmx, dv);
    }
#pragma unroll
    for (int s = 1; s < 64; s <<= 1) {
        dmn = fminf(dmn, __shfl_xor(dmn, s, 64));
        dmx = fmaxf(dmx, __shfl_xor(dmx, s, 64));
    }
    float scale = 2097151.0f / fmaxf(dmx - dmn, 1e-30f);

    unsigned key[32];
    unsigned c0 = KINF, c1 = KINF, c2 = KINF, c3 = KINF;
#pragma unroll
    for (int m = 0; m < 32; ++m) {
        unsigned qd = (unsigned)fminf((d[m] - dmn) * scale, 2097151.f);
        unsigned kk = (qd << 11) | (unsigned)(lane + (m << 6));
        key[m] = kk;
        if (kk < c3) {
            if (kk < c2) {
                c3 = c2;
                if (kk < c1) {
                    c2 = c1;
                    if (kk < c0) { c1 = c0; c0 = kk; } else c1 = kk;
                } else c2 = kk;
            } else c3 = kk;
        }
    }
    unsigned hw = c3;        // high-water: largest key ever cached
    int ncached = 4;
    int* o = out + (size_t)qidx * k;

    for (int r = 0; r < k; ++r) {
        bool need = (c0 == KINF) && (ncached < 32);
        if (__any(need)) {
            unsigned best = KINF;
#pragma unroll
            for (int m = 0; m < 32; ++m) {
                unsigned v = key[m];
                best = (v > hw && v < best) ? v : best;
            }
            if (need) {
                c0 = best;
                hw = best;
                ncached = (best == KINF) ? 32 : ncached + 1;
            }
        }
        unsigned g = wave_min_u32(c0);
        if (lane == 0) o[r] = (int)(g & 0x7FFu);
        if (((g & 0x7FFu) & 63u) == (unsigned)lane) {  // owner pops its c0 (== g)
            c0 = c1; c1 = c2; c2 = c3; c3 = KINF;
        }
    }
}

// ---------- gather points via index array ----------
__global__ void gather_points_kernel(const float* __restrict__ pts, int db_bstride,
                                     const int* __restrict__ idx, int idx_bstride, int idx_off,
                                     int m, float* __restrict__ out, int nbatch) {
    int t = blockIdx.x * blockDim.x + threadIdx.x;
    if (t >= nbatch * m) return;
    int b = t / m, j = t % m;
    int s = idx[(size_t)b * idx_bstride + idx_off + j];
    const float* p = pts + ((size_t)b * db_bstride + s) * 3;
    out[(size_t)t * 3 + 0] = p[0];
    out[(size_t)t * 3 + 1] = p[1];
    out[(size_t)t * 3 + 2] = p[2];
}

// ---------- fp32 -> fp16 weight conversion (strided slice) ----------
__global__ void cvt_w_kernel(const float* __restrict__ in, int ld, int off, int K,
                             f16* __restrict__ out, int total) {
    int t = blockIdx.x * blockDim.x + threadIdx.x;
    if (t >= total) return;
    int n = t / K, k = t % K;
    out[t] = (f16)in[(size_t)n * ld + off + k];
}

// ---------- layer1: H1 = relu(bn(x @ W1^T + b1)) in fp16, fused ----------
__global__ void layer1_kernel(const float* __restrict__ X, const float* __restrict__ W1,
                              const float* __restrict__ b1, const float* __restrict__ g1,
                              const float* __restrict__ be1, const float* __restrict__ m1,
                              const float* __restrict__ v1, f16* __restrict__ H1, int M) {
    __shared__ float w[384], bb[128], sg[128], sb[128], sm[128], sv[128];
    for (int i = threadIdx.x; i < 384; i += 256) w[i] = W1[i];
    if (threadIdx.x < 128) {
        int c = threadIdx.x;
        bb[c] = b1[c]; sg[c] = g1[c]; sb[c] = be1[c]; sm[c] = m1[c]; sv[c] = v1[c];
    }
    __syncthreads();
    int t = blockIdx.x * 256 + threadIdx.x;
    if (t >= M * 16) return;
    int row = t >> 4, cg = (t & 15) * 8;
    float x0 = X[(size_t)row * 3], x1 = X[(size_t)row * 3 + 1], x2 = X[(size_t)row * 3 + 2];
    f16x8 outv;
#pragma unroll
    for (int j = 0; j < 8; ++j) {
        int c = cg + j;
        float tv = x0 * w[c * 3] + x1 * w[c * 3 + 1] + x2 * w[c * 3 + 2] + bb[c];
        float vv = (tv - sm[c]) * rsqrtf(sv[c] + 1e-5f) * sg[c] + sb[c];
        outv[j] = (f16)fmaxf(vv, 0.f);
    }
    *(f16x8*)&H1[(size_t)row * 128 + cg] = outv;
}

// ---------- MFMA GEMM ----------
__global__ __launch_bounds__(256) void mfma_gemm_kernel(
        const f16* __restrict__ A, const f16* __restrict__ W, int K, int N,
        const float* __restrict__ bias, const float* __restrict__ bias2d,
        const float* __restrict__ bng, const float* __restrict__ bnb,
        const float* __restrict__ bnm, const float* __restrict__ bnv,
        f16* __restrict__ Cout, unsigned* __restrict__ maxkey,
        int rows_per_batch, int relu) {
    __shared__ f16 Als[128 * 40];
    __shared__ f16 Bls[128 * 40];
    int tid = threadIdx.x;
    int lane = tid & 63;
    int wave = tid >> 6;
    int wm = wave & 1, wn = wave >> 1;
    int c16 = lane & 15, quad = lane >> 4;
    int row0 = blockIdx.y * 128, col0 = blockIdx.x * 128;
    int sr = tid >> 2;
    int skc = (tid & 3) * 8;

    f32x4 acc[4][4];
#pragma unroll
    for (int i = 0; i < 4; ++i)
#pragma unroll
        for (int j = 0; j < 4; ++j) acc[i][j] = (f32x4){0.f, 0.f, 0.f, 0.f};

    for (int k0 = 0; k0 < K; k0 += 32) {
#pragma unroll
        for (int i = 0; i < 2; ++i) {
            int r2 = sr + i * 64;
            f16x8 av = *(const f16x8*)(A + (size_t)(row0 + r2) * K + k0 + skc);
            *(f16x8*)&Als[r2 * 40 + skc] = av;
            f16x8 bv = *(const f16x8*)(W + (size_t)(col0 + r2) * K + k0 + skc);
            *(f16x8*)&Bls[r2 * 40 + skc] = bv;
        }
        __syncthreads();
        f16x8 af[4], bf[4];
#pragma unroll
        for (int s = 0; s < 4; ++s) {
            af[s] = *(const f16x8*)&Als[(wm * 64 + s * 16 + c16) * 40 + quad * 8];
            bf[s] = *(const f16x8*)&Bls[(wn * 64 + s * 16 + c16) * 40 + quad * 8];
        }
#pragma unroll
        for (int ms = 0; ms < 4; ++ms)
#pragma unroll
            for (int ns = 0; ns < 4; ++ns)
                acc[ms][ns] = __builtin_amdgcn_mfma_f32_16x16x32_f16(af[ms], bf[ns],
                                                                     acc[ms][ns], 0, 0, 0);
        __syncthreads();
    }

    int b = row0 / rows_per_batch;
#pragma unroll
    for (int ns = 0; ns < 4; ++ns) {
        int col = col0 + wn * 64 + ns * 16 + c16;
        float bv = bias ? bias[col] : 0.f;
        float b2v = bias2d ? bias2d[(size_t)b * N + col] : 0.f;
        float mx = -3e38f;
#pragma unroll
        for (int ms = 0; ms < 4; ++ms) {
#pragma unroll
            for (int j = 0; j < 4; ++j) {
                float v = acc[ms][ns][j] + bv + b2v;
                if (bng) v = (v - bnm[col]) * rsqrtf(bnv[col] + 1e-5f) * bng[col] + bnb[col];
                if (relu) v = fmaxf(v, 0.f);
                if (Cout)
                    Cout[(size_t)(row0 + wm * 64 + ms * 16 + quad * 4 + j) * N + col] = (f16)v;
                mx = fmaxf(mx, v);
            }
        }
        if (maxkey) {
            mx = fmaxf(mx, __shfl_xor(mx, 16, 64));
            mx = fmaxf(mx, __shfl_xor(mx, 32, 64));
            if (quad == 0) atomicMax(&maxkey[(size_t)b * N + col], fkey(mx));
        }
    }
}

// ---------- skinny GEMM v2: wave per column, coalesced float4 ----------
__global__ void skinny_v2_kernel(const float* __restrict__ A, const float* __restrict__ W,
                                 int ldw, int woff, const float* __restrict__ bias,
                                 float* __restrict__ C, int K, int N, int relu) {
    int wave = threadIdx.x >> 6, lane = threadIdx.x & 63;
    int col = blockIdx.x * 4 + wave;
    if (col >= N) return;
    const float* w = W + (size_t)col * ldw + woff;
    float acc[16];
#pragma unroll
    for (int m = 0; m < 16; ++m) acc[m] = 0.f;
    for (int k0 = 0; k0 < K; k0 += 256) {
        f32x4 wv = *(const f32x4*)(w + k0 + lane * 4);
#pragma unroll
        for (int m = 0; m < 16; ++m) {
            f32x4 av = *(const f32x4*)(A + (size_t)m * K + k0 + lane * 4);
            acc[m] += av[0] * wv[0] + av[1] * wv[1] + av[2] * wv[2] + av[3] * wv[3];
        }
    }
#pragma unroll
    for (int m = 0; m < 16; ++m)
#pragma unroll
        for (int s = 1; s < 64; s <<= 1) acc[m] += __shfl_xor(acc[m], s, 64);
    if (lane == 0) {
        float bv = bias[col];
#pragma unroll
        for (int m = 0; m < 16; ++m) {
            float v = acc[m] + bv;
            if (relu) v = fmaxf(v, 0.f);
            C[(size_t)m * N + col] = v;
        }
    }
}

__global__ void decode_kernel(const unsigned* __restrict__ k, float* __restrict__ f, int n) {
    int t = blockIdx.x * blockDim.x + threadIdx.x;
    if (t < n) f[t] = fkey_inv(k[t]);
}

// ---------- chamfer v2: 8 lanes per A-point, j-strided, shfl-min ----------
__global__ void chamfer_min_kernel(const float* __restrict__ A, int na,
                                   const float* __restrict__ Bp, int nb,
                                   float* __restrict__ slot) {
    int t = blockIdx.x * 256 + threadIdx.x;
    int pt = t >> 3, sl = t & 7;
    float val = 0.f;
    if (pt < BSZ * na) {
        int b = pt / na;
        const float* a = A + (size_t)pt * 3;
        float ax = a[0], ay = a[1], az = a[2];
        float aa = ax * ax + ay * ay + az * az;
        const float* Bb = Bp + (size_t)b * nb * 3;
        float m = 3e38f;
        for (int j = sl; j < nb; j += 8) {
            float bx = Bb[j * 3 + 0], by = Bb[j * 3 + 1], bz = Bb[j * 3 + 2];
            float d = aa + bx * bx + by * by + bz * bz - 2.0f * (ax * bx + ay * by + az * bz);
            m = fminf(m, d);
        }
#pragma unroll
        for (int s = 1; s < 8; s <<= 1) m = fminf(m, __shfl_xor(m, s, 64));
        if (sl == 0) val = sqrtf(fmaxf(m, 1e-12f));
    }
    __shared__ float sdata[256];
    sdata[threadIdx.x] = val;
    __syncthreads();
    for (int s = 128; s > 0; s >>= 1) {
        if (threadIdx.x < s) sdata[threadIdx.x] += sdata[threadIdx.x + s];
        __syncthreads();
    }
    if (threadIdx.x == 0) atomicAdd(slot, sdata[0]);
}

// ---------- smooth-L1 latent loss sum ----------
__global__ void latent_kernel(const float* __restrict__ f1, const float* __restrict__ f2,
                              int n, float* __restrict__ slot) {
    int t = blockIdx.x * blockDim.x + threadIdx.x;
    float val = 0.f;
    if (t < n) {
        float d = f1[t] - f2[t];
        float ad = fabsf(d);
        val = (ad < 1.f) ? (0.5f * d * d) : (ad - 0.5f);
    }
    __shared__ float sdata[256];
    sdata[threadIdx.x] = val;
    __syncthreads();
    for (int s = 128; s > 0; s >>= 1) {
        if (threadIdx.x < s) sdata[threadIdx.x] += sdata[threadIdx.x + s];
        __syncthreads();
    }
    if (threadIdx.x == 0) atomicAdd(slot, sdata[0]);
}

// ---------- 3x3 symmetric smallest eigenvector (double, analytic) ----------
__device__ void smallest_evec(double cxx, double cxy, double cxz,
                              double cyy, double cyz, double czz, double ev[3]) {
    double p1 = cxy * cxy + cxz * cxz + cyz * cyz;
    double q = (cxx + cyy + czz) / 3.0;
    double p2 = (cxx - q) * (cxx - q) + (cyy - q) * (cyy - q) + (czz - q) * (czz - q) + 2.0 * p1;
    double lam = q;
    if (p2 > 0.0) {
        double p = sqrt(p2 / 6.0);
        double b00 = (cxx - q) / p, b11 = (cyy - q) / p, b22 = (czz - q) / p;
        double b01 = cxy / p, b02 = cxz / p, b12 = cyz / p;
        double detB = b00 * (b11 * b22 - b12 * b12) - b01 * (b01 * b22 - b12 * b02)
                    + b02 * (b01 * b12 - b11 * b02);
        double r = detB * 0.5;
        r = r < -1.0 ? -1.0 : (r > 1.0 ? 1.0 : r);
        double phi = acos(r) / 3.0;
        lam = q + 2.0 * p * cos(phi + 2.0943951023931953);
    }
    double r0x = cxx - lam, r0y = cxy, r0z = cxz;
    double r1x = cxy, r1y = cyy - lam, r1z = cyz;
    double r2x = cxz, r2y = cyz, r2z = czz - lam;
    double c0x = r0y * r1z - r0z * r1y, c0y = r0z * r1x - r0x * r1z, c0z = r0x * r1y - r0y * r1x;
    double c1x = r0y * r2z - r0z * r2y, c1y = r0z * r2x - r0x * r2z, c1z = r0x * r2y - r0y * r2x;
    double c2x = r1y * r2z - r1z * r2y, c2y = r1z * r2x - r1x * r2z, c2z = r1x * r2y - r1y * r2x;
    double n0 = c0x * c0x + c0y * c0y + c0z * c0z;
    double n1 = c1x * c1x + c1y * c1y + c1z * c1z;
    double n2 = c2x * c2x + c2y * c2y + c2z * c2z;
    double bx = c0x, by = c0y, bz = c0z, bn = n0;
    if (n1 > bn) { bx = c1x; by = c1y; bz = c1z; bn = n1; }
    if (n2 > bn) { bx = c2x; by = c2y; bz = c2z; bn = n2; }
    if (bn < 1e-280) { ev[0] = 1.0; ev[1] = 0.0; ev[2] = 0.0; return; }
    double inv = 1.0 / sqrt(bn);
    ev[0] = bx * inv; ev[1] = by * inv; ev[2] = bz * inv;
}

// ---------- normals ----------
__global__ void normals_kernel(const float* __restrict__ pred, const int* __restrict__ knn,
                               float* __restrict__ nrm) {
    int t = blockIdx.x * blockDim.x + threadIdx.x;
    if (t >= BSZ * NPTS) return;
    int b = t / NPTS, i = t % NPTS;
    const float* P = pred + (size_t)b * NPTS * 3;
    const int* id = knn + (size_t)t * 32;
    float px[32], py[32], pz[32];
    double sx = 0, sy = 0, sz = 0;
    for (int k = 0; k < 32; ++k) {
        int j = id[k];
        px[k] = P[j * 3 + 0]; py[k] = P[j * 3 + 1]; pz[k] = P[j * 3 + 2];
        sx += px[k]; sy += py[k]; sz += pz[k];
    }
    double mx = sx / 32.0, my = sy / 32.0, mz = sz / 32.0;
    double cxx = 0, cxy = 0, cxz = 0, cyy = 0, cyz = 0, czz = 0;
    for (int k = 0; k < 32; ++k) {
        double dx = px[k] - mx, dy = py[k] - my, dz = pz[k] - mz;
        cxx += dx * dx; cxy += dx * dy; cxz += dx * dz;
        cyy += dy * dy; cyz += dy * dz; czz += dz * dz;
    }
    cxx /= 32.0; cxy /= 32.0; cxz /= 32.0; cyy /= 32.0; cyz /= 32.0; czz /= 32.0;
    double ev[3];
    smallest_evec(cxx, cxy, cxz, cyy, cyz, czz, ev);
    float qx = P[i * 3 + 0], qy = P[i * 3 + 1], qz = P[i * 3 + 2];
    double proj = 0.0;
    for (int k = 0; k < 32; ++k)
        proj += (px[k] - qx) * ev[0] + (py[k] - qy) * ev[1] + (pz[k] - qz) * ev[2];
    double s = (proj >= 0.0) ? 1.0 : -1.0;
    nrm[(size_t)t * 3 + 0] = (float)(ev[0] * s);
    nrm[(size_t)t * 3 + 1] = (float)(ev[1] * s);
    nrm[(size_t)t * 3 + 2] = (float)(ev[2] * s);
}

// ---------- manifold loss: reads first 8 of the 32-NN list ----------
__global__ void manifold_kernel(const float* __restrict__ nrm, const int* __restrict__ knn,
                                int kstride, float* __restrict__ slot) {
    int t = blockIdx.x * blockDim.x + threadIdx.x;
    float val = 0.f;
    if (t < BSZ * NPTS) {
        int b = t / NPTS;
        const float* NB = nrm + (size_t)b * NPTS * 3;
        const int* id = knn + (size_t)t * kstride;
        int j0 = id[0];
        float ax = NB[j0 * 3 + 0], ay = NB[j0 * 3 + 1], az = NB[j0 * 3 + 2];
        float an = fmaxf(sqrtf(ax * ax + ay * ay + az * az), 1e-6f);
        float x[8]; float s = 0.f;
        for (int k = 0; k < 8; ++k) {
            int j = id[k];
            float bx = NB[j * 3 + 0], by = NB[j * 3 + 1], bz = NB[j * 3 + 2];
            float bn_ = fmaxf(sqrtf(bx * bx + by * by + bz * bz), 1e-6f);
            float c = (ax * bx + ay * by + az * bz) / (an * bn_);
            x[k] = 1.f - c; s += x[k];
        }
        float mean = s / 8.f;
        float var = 0.f;
        for (int k = 0; k < 8; ++k) { float d = x[k] - mean; var += d * d; }
        val = sqrtf(var / 7.f);
    }
    __shared__ float sdata[256];
    sdata[threadIdx.x] = val;
    __syncthreads();
    for (int s2 = 128; s2 > 0; s2 >>= 1) {
        if (threadIdx.x < s2) sdata[threadIdx.x] += sdata[threadIdx.x + s2];
        __syncthreads();
    }
    if (threadIdx.x == 0) atomicAdd(slot, sdata[0]);
}

__global__ void finalize_kernel(const float* __restrict__ acc, float* __restrict__ out) {
    float l_recon = 0.5f * (acc[0] / (16.f * 2048.f) + acc[1] / (16.f * 2432.f));
    float l_match = 0.5f * (acc[2] / (16.f * 1024.f) + acc[3] / (16.f * 1216.f));
    float l_latent = acc[4] / (16.f * 1024.f);
    float l_man = 0.1f * (acc[5] / (16.f * 2048.f));
    out[0] = l_recon + l_match + l_latent + l_man;
    out[1] = l_recon;
    out[2] = l_match;
    out[3] = l_latent;
    out[4] = l_man;
}

// ================= host =================
extern "C" void kernel_launch(void* const* d_in, const int* in_sizes, int n_in,
                              void* d_out, int out_size, void* d_ws, size_t ws_size,
                              hipStream_t stream) {
    (void)in_sizes; (void)n_in; (void)out_size; (void)ws_size;
    const float* pts = (const float*)d_in[0];
    const float* W1 = (const float*)d_in[1];
    const float* b1 = (const float*)d_in[2];
    const float* g1 = (const float*)d_in[3];
    const float* be1 = (const float*)d_in[4];
    const float* m1 = (const float*)d_in[5];
    const float* v1 = (const float*)d_in[6];
    const float* W2 = (const float*)d_in[7];
    const float* b2 = (const float*)d_in[8];
    const float* W3 = (const float*)d_in[9];
    const float* b3 = (const float*)d_in[10];
    const float* g2 = (const float*)d_in[11];
    const float* be2 = (const float*)d_in[12];
    const float* m2 = (const float*)d_in[13];
    const float* v2 = (const float*)d_in[14];
    const float* W4 = (const float*)d_in[15];
    const float* b4 = (const float*)d_in[16];
    const float* D1W = (const float*)d_in[17];
    const float* D1b = (const float*)d_in[18];
    const float* D2W = (const float*)d_in[19];
    const float* D2b = (const float*)d_in[20];
    const float* D3W = (const float*)d_in[21];
    const float* D3b = (const float*)d_in[22];
    const float* D4W = (const float*)d_in[23];
    const float* D4b = (const float*)d_in[24];

    char* ws = (char*)d_ws;
    size_t off = 0;
    auto alloc = [&](size_t bytes) -> void* {
        void* p = ws + off;
        off += (bytes + 255) & ~(size_t)255;
        return p;
    };
    float* center   = (float*)alloc((size_t)BSZ * NG * 3 * 4);
    int*   knnc     = (int*)  alloc((size_t)BSZ * NG * GS * 4);
    float* rebuild0 = (float*)alloc((size_t)BSZ * 2048 * 3 * 4);
    float* rebuild1 = (float*)alloc((size_t)BSZ * 1024 * 3 * 4);
    f16*   W2h      = (f16*)  alloc((size_t)256 * 128 * 2);
    f16*   W3h      = (f16*)  alloc((size_t)512 * 256 * 2);
    f16*   W4h      = (f16*)  alloc((size_t)1024 * 512 * 2);
    f16*   H1h      = (f16*)  alloc((size_t)BSZ * 2048 * 128 * 2);
    f16*   H2h      = (f16*)  alloc((size_t)BSZ * 2048 * 256 * 2);
    f16*   H3h      = (f16*)  alloc((size_t)BSZ * 2048 * 512 * 2);
    unsigned* gmaxkey = (unsigned*)alloc((size_t)BSZ * 256 * 4);
    float* gmaxb    = (float*)alloc((size_t)BSZ * 256 * 4);
    float* gpart    = (float*)alloc((size_t)BSZ * 512 * 4);
    unsigned* featkey = (unsigned*)alloc((size_t)BSZ * 1024 * 4);
    float* feat     = (float*)alloc((size_t)BSZ * 1024 * 4);
    float* featrec  = (float*)alloc((size_t)BSZ * 1024 * 4);
    float* dh1      = (float*)alloc((size_t)BSZ * 2048 * 4);
    float* dh2      = (float*)alloc((size_t)BSZ * 2048 * 4);
    float* dh3      = (float*)alloc((size_t)BSZ * 2048 * 4);
    float* pred     = (float*)alloc((size_t)BSZ * 6144 * 4);
    int*   idxa     = (int*)  alloc((size_t)BSZ * 64 * NBRK * 4);
    float* gatha    = (float*)alloc((size_t)BSZ * 64 * NBRK * 3 * 4);
    int*   idxb     = (int*)  alloc((size_t)BSZ * 32 * NBRK * 4);
    float* gathb    = (float*)alloc((size_t)BSZ * 32 * NBRK * 3 * 4);
    int*   idxc     = (int*)  alloc((size_t)BSZ * 32 * 32 * 4);
    float* gathc    = (float*)alloc((size_t)BSZ * 1024 * 3 * 4);
    int*   knn32    = (int*)  alloc((size_t)BSZ * 2048 * 32 * 4);
    float* nrmbuf   = (float*)alloc((size_t)BSZ * 2048 * 3 * 4);
    float* accum    = (float*)alloc(8 * 4);

    hipMemsetAsync(accum, 0, 8 * 4, stream);

    cvt_w_kernel<<<(256 * 128 + 255) / 256, 256, 0, stream>>>(W2, 128, 0, 128, W2h, 256 * 128);
    cvt_w_kernel<<<(512 * 256 + 255) / 256, 256, 0, stream>>>(W3, 512, 256, 256, W3h, 512 * 256);
    cvt_w_kernel<<<(1024 * 512 + 255) / 256, 256, 0, stream>>>(W4, 512, 0, 512, W4h, 1024 * 512);

    auto knn = [&](const float* Q, int q_bstride, int q_off, int nq,
                   const float* DB, int k, int* out) {
        int total = BSZ * nq;
        knn_kernel_v8<<<(total + 3) / 4, 256, 0, stream>>>(Q, q_bstride, q_off, nq,
                                                           DB, k, out, BSZ);
    };

    // FPS + grouping
    fps_kernel_v3<<<BSZ, 64, 0, stream>>>(pts, center);
    knn(center, NG, 0, NG, pts, GS, knnc);
    gather_points_kernel<<<(BSZ * 2048 + 255) / 256, 256, 0, stream>>>(pts, NPTS, knnc, NG * GS,
                                                                       0, 2048, rebuild0, BSZ);
    gather_points_kernel<<<(BSZ * 1024 + 255) / 256, 256, 0, stream>>>(pts, NPTS, knnc, NG * GS,
                                                                       2048, 1024, rebuild1, BSZ);

    auto enc = [&](const float* X, int n, float* featout) {
        int M = BSZ * n;
        layer1_kernel<<<M / 16, 256, 0, stream>>>(X, W1, b1, g1, be1, m1, v1, H1h, M);
        hipMemsetAsync(gmaxkey, 0, (size_t)BSZ * 256 * 4, stream);
        mfma_gemm_kernel<<<dim3(256 / 128, M / 128), 256, 0, stream>>>(
            H1h, W2h, 128, 256, b2, nullptr, nullptr, nullptr, nullptr, nullptr,
            H2h, gmaxkey, n, 0);
        decode_kernel<<<(BSZ * 256 + 255) / 256, 256, 0, stream>>>(gmaxkey, gmaxb, BSZ * 256);
        skinny_v2_kernel<<<(512 + 3) / 4, 256, 0, stream>>>(gmaxb, W3, 512, 0, b3,
                                                            gpart, 256, 512, 0);
        mfma_gemm_kernel<<<dim3(512 / 128, M / 128), 256, 0, stream>>>(
            H2h, W3h, 256, 512, nullptr, gpart, g2, be2, m2, v2, H3h, nullptr, n, 1);
        hipMemsetAsync(featkey, 0, (size_t)BSZ * 1024 * 4, stream);
        mfma_gemm_kernel<<<dim3(1024 / 128, M / 128), 256, 0, stream>>>(
            H3h, W4h, 512, 1024, b4, nullptr, nullptr, nullptr, nullptr, nullptr,
            nullptr, featkey, n, 0);
        decode_kernel<<<(BSZ * 1024 + 255) / 256, 256, 0, stream>>>(featkey, featout, BSZ * 1024);
    };

    enc(rebuild0, 2048, feat);

    // decoder (skinny M=16, fp32, coalesced)
    skinny_v2_kernel<<<2048 / 4, 256, 0, stream>>>(feat, D1W, 1024, 0, D1b, dh1, 1024, 2048, 1);
    skinny_v2_kernel<<<2048 / 4, 256, 0, stream>>>(dh1, D2W, 2048, 0, D2b, dh2, 2048, 2048, 1);
    skinny_v2_kernel<<<2048 / 4, 256, 0, stream>>>(dh2, D3W, 2048, 0, D3b, dh3, 2048, 2048, 1);
    skinny_v2_kernel<<<6144 / 4, 256, 0, stream>>>(dh3, D4W, 2048, 0, D4b, pred, 2048, 6144, 0);

    // l_recon
    knn(center, NG, 0, 64, pred, NBRK, idxa);
    gather_points_kernel<<<(BSZ * 2432 + 255) / 256, 256, 0, stream>>>(pred, 2048, idxa, 64 * NBRK,
                                                                       0, 2432, gatha, BSZ);
    chamfer_min_kernel<<<(BSZ * 2048 * 8 + 255) / 256, 256, 0, stream>>>(rebuild0, 2048,
                                                                         gatha, 2432, accum + 0);
    chamfer_min_kernel<<<(BSZ * 2432 * 8 + 255) / 256, 256, 0, stream>>>(gatha, 2432,
                                                                         rebuild0, 2048, accum + 1);
    // l_match
    knn(center, NG, 64, 32, pred, NBRK, idxb);
    gather_points_kernel<<<(BSZ * 1216 + 255) / 256, 256, 0, stream>>>(pred, 2048, idxb, 32 * NBRK,
                                                                       0, 1216, gathb, BSZ);
    chamfer_min_kernel<<<(BSZ * 1024 * 8 + 255) / 256, 256, 0, stream>>>(rebuild1, 1024,
                                                                         gathb, 1216, accum + 2);
    chamfer_min_kernel<<<(BSZ * 1216 * 8 + 255) / 256, 256, 0, stream>>>(gathb, 1216,
                                                                         rebuild1, 1024, accum + 3);
    // l_latent
    knn(center, NG, 96, 32, pred, 32, idxc);
    gather_points_kernel<<<(BSZ * 1024 + 255) / 256, 256, 0, stream>>>(pred, 2048, idxc, 32 * 32,
                                                                       0, 1024, gathc, BSZ);
    enc(gathc, 1024, featrec);
    latent_kernel<<<(BSZ * 1024 + 255) / 256, 256, 0, stream>>>(feat, featrec, BSZ * 1024,
                                                                accum + 4);
    // l_man: one self-KNN (k=32); manifold uses first 8 (stable top-k prefix)
    knn(pred, 2048, 0, 2048, pred, 32, knn32);
    normals_kernel<<<(BSZ * 2048 + 255) / 256, 256, 0, stream>>>(pred, knn32, nrmbuf);
    manifold_kernel<<<(BSZ * 2048 + 255) / 256, 256, 0, stream>>>(nrmbuf, knn32, 32, accum + 5);

    finalize_kernel<<<1, 1, 0, stream>>>(accum, (float*)d_out);
}

// Round 9
// 992.930 us; speedup vs baseline: 1.5854x; 1.5854x over previous
//
#include <hip/hip_runtime.h>
#include <math.h>

#define BSZ 16
#define NPTS 2048
#define NG 128
#define GS 32
#define NBRK 38

typedef _Float16 f16;
typedef _Float16 f16x8 __attribute__((ext_vector_type(8)));
typedef float f32x4 __attribute__((ext_vector_type(4)));

// ---------- helpers ----------
__device__ __forceinline__ unsigned fkey(float x) {
    unsigned u = __float_as_uint(x);
    return (u >> 31) ? ~u : (u | 0x80000000u);
}
__device__ __forceinline__ float fkey_inv(unsigned k) {
    unsigned u = (k >> 31) ? (k ^ 0x80000000u) : ~k;
    return __uint_as_float(u);
}

// 64-lane min via DPP (no LDS/DS pipe)
__device__ __forceinline__ unsigned wave_min_u32(unsigned v) {
    unsigned t;
    t = (unsigned)__builtin_amdgcn_update_dpp(-1, (int)v, 0x111, 0xF, 0xF, false);
    v = v < t ? v : t;
    t = (unsigned)__builtin_amdgcn_update_dpp(-1, (int)v, 0x112, 0xF, 0xF, false);
    v = v < t ? v : t;
    t = (unsigned)__builtin_amdgcn_update_dpp(-1, (int)v, 0x114, 0xF, 0xF, false);
    v = v < t ? v : t;
    t = (unsigned)__builtin_amdgcn_update_dpp(-1, (int)v, 0x118, 0xF, 0xF, false);
    v = v < t ? v : t;
    t = (unsigned)__builtin_amdgcn_update_dpp(-1, (int)v, 0x142, 0xA, 0xF, false);
    v = v < t ? v : t;
    t = (unsigned)__builtin_amdgcn_update_dpp(-1, (int)v, 0x143, 0xC, 0xF, false);
    v = v < t ? v : t;
    return (unsigned)__builtin_amdgcn_readlane((int)v, 63);
}

// ---------- FPS v4: 8 pts/lane (no spill), coord-carrying butterfly, 1 barrier/iter ----------
// 256 threads. Winner's coordinates ride the reduction (no dependent global load).
// Double-buffered LDS result slots (parity g&1) make a single __syncthreads safe:
// a wave one iteration ahead writes the OTHER buffer.
__global__ __launch_bounds__(256) void fps_kernel_v4(const float* __restrict__ pts,
                                                     float* __restrict__ center) {
    int b = blockIdx.x;
    const float* P = pts + (size_t)b * NPTS * 3;
    int tid = threadIdx.x;
    int lane = tid & 63, wave = tid >> 6;
    float px[8], py[8], pz[8], mind[8];
#pragma unroll
    for (int m = 0; m < 8; ++m) {
        int i = tid + 256 * m;
        px[m] = P[i * 3 + 0]; py[m] = P[i * 3 + 1]; pz[m] = P[i * 3 + 2];
        mind[m] = 1e10f;
    }
    __shared__ float s_best[2][4], s_x[2][4], s_y[2][4], s_z[2][4];
    __shared__ int   s_i[2][4];
    float fx = P[0], fy = P[1], fz = P[2];   // far = index 0 initially
    for (int g = 0; g < NG; ++g) {
        if (tid == 0) {
            center[((size_t)b * NG + g) * 3 + 0] = fx;
            center[((size_t)b * NG + g) * 3 + 1] = fy;
            center[((size_t)b * NG + g) * 3 + 2] = fz;
        }
        float best = -1.0f; int bi = 0;
        float bx = 0.f, by = 0.f, bz = 0.f;
#pragma unroll
        for (int m = 0; m < 8; ++m) {
            float dx = px[m] - fx, dy = py[m] - fy, dz = pz[m] - fz;
            float d = dx * dx + dy * dy + dz * dz;
            float md = fminf(mind[m], d);
            mind[m] = md;
            if (md > best) {                 // ascending m: first max kept (lowest idx)
                best = md; bi = tid + 256 * m;
                bx = px[m]; by = py[m]; bz = pz[m];
            }
        }
#pragma unroll
        for (int s = 1; s < 64; s <<= 1) {
            float ov = __shfl_xor(best, s, 64);
            int   oi = __shfl_xor(bi, s, 64);
            float ox = __shfl_xor(bx, s, 64);
            float oy = __shfl_xor(by, s, 64);
            float oz = __shfl_xor(bz, s, 64);
            if (ov > best || (ov == best && oi < bi)) {
                best = ov; bi = oi; bx = ox; by = oy; bz = oz;
            }
        }
        int buf = g & 1;
        if (lane == 0) {
            s_best[buf][wave] = best; s_i[buf][wave] = bi;
            s_x[buf][wave] = bx; s_y[buf][wave] = by; s_z[buf][wave] = bz;
        }
        __syncthreads();
        float fb = s_best[buf][0]; int fi = s_i[buf][0]; int fw = 0;
#pragma unroll
        for (int w = 1; w < 4; ++w) {
            float ov = s_best[buf][w]; int oi = s_i[buf][w];
            if (ov > fb || (ov == fb && oi < fi)) { fb = ov; fi = oi; fw = w; }
        }
        fx = s_x[buf][fw]; fy = s_y[buf][fw]; fz = s_z[buf][fw];
    }
}

// ---------- KNN v8: per-query adaptive 21-bit quantization + DPP wave-min ----------
__global__ void knn_kernel_v8(const float* __restrict__ Q, int q_bstride, int q_off, int nq,
                              const float* __restrict__ DB, int k,
                              int* __restrict__ out, int nbatch) {
    const unsigned KINF = 0xFFFFFFFFu;
    int wave = threadIdx.x >> 6, lane = threadIdx.x & 63;
    int qidx = blockIdx.x * 4 + wave;
    if (qidx >= nbatch * nq) return;     // wave-uniform
    int b = qidx / nq, qi = qidx % nq;
    const float* q = Q + ((size_t)b * q_bstride + q_off + qi) * 3;
    float qx = q[0], qy = q[1], qz = q[2];
    float qq = qx * qx + qy * qy + qz * qz;
    const float* db = DB + (size_t)b * NPTS * 3;

    float d[32];
    float dmn = 3e38f, dmx = -3e38f;
#pragma unroll
    for (int m = 0; m < 32; ++m) {
        int j = lane + (m << 6);
        float bx = db[j * 3 + 0], by = db[j * 3 + 1], bz = db[j * 3 + 2];
        float dv = qq + bx * bx + by * by + bz * bz - 2.0f * (qx * bx + qy * by + qz * bz);
        d[m] = dv;
        dmn = fminf(dmn, dv);
        dmx = fmaxf(dmx, dv);
    }
#pragma unroll
    for (int s = 1; s < 64; s <<= 1) {
        dmn = fminf(dmn, __shfl_xor(dmn, s, 64));
        dmx = fmaxf(dmx, __shfl_xor(dmx, s, 64));
    }
    float scale = 2097151.0f / fmaxf(dmx - dmn, 1e-30f);

    unsigned key[32];
    unsigned c0 = KINF, c1 = KINF, c2 = KINF, c3 = KINF;
#pragma unroll
    for (int m = 0; m < 32; ++m) {
        unsigned qd = (unsigned)fminf((d[m] - dmn) * scale, 2097151.f);
        unsigned kk = (qd << 11) | (unsigned)(lane + (m << 6));
        key[m] = kk;
        if (kk < c3) {
            if (kk < c2) {
                c3 = c2;
                if (kk < c1) {
                    c2 = c1;
                    if (kk < c0) { c1 = c0; c0 = kk; } else c1 = kk;
                } else c2 = kk;
            } else c3 = kk;
        }
    }
    unsigned hw = c3;        // high-water: largest key ever cached
    int ncached = 4;
    int* o = out + (size_t)qidx * k;

    for (int r = 0; r < k; ++r) {
        bool need = (c0 == KINF) && (ncached < 32);
        if (__any(need)) {
            unsigned best = KINF;
#pragma unroll
            for (int m = 0; m < 32; ++m) {
                unsigned v = key[m];
                best = (v > hw && v < best) ? v : best;
            }
            if (need) {
                c0 = best;
                hw = best;
                ncached = (best == KINF) ? 32 : ncached + 1;
            }
        }
        unsigned g = wave_min_u32(c0);
        if (lane == 0) o[r] = (int)(g & 0x7FFu);
        if (((g & 0x7FFu) & 63u) == (unsigned)lane) {  // owner pops its c0 (== g)
            c0 = c1; c1 = c2; c2 = c3; c3 = KINF;
        }
    }
}

// ---------- gather points via index array ----------
__global__ void gather_points_kernel(const float* __restrict__ pts, int db_bstride,
                                     const int* __restrict__ idx, int idx_bstride, int idx_off,
                                     int m, float* __restrict__ out, int nbatch) {
    int t = blockIdx.x * blockDim.x + threadIdx.x;
    if (t >= nbatch * m) return;
    int b = t / m, j = t % m;
    int s = idx[(size_t)b * idx_bstride + idx_off + j];
    const float* p = pts + ((size_t)b * db_bstride + s) * 3;
    out[(size_t)t * 3 + 0] = p[0];
    out[(size_t)t * 3 + 1] = p[1];
    out[(size_t)t * 3 + 2] = p[2];
}

// ---------- fp32 -> fp16 weight conversion (strided slice) ----------
__global__ void cvt_w_kernel(const float* __restrict__ in, int ld, int off, int K,
                             f16* __restrict__ out, int total) {
    int t = blockIdx.x * blockDim.x + threadIdx.x;
    if (t >= total) return;
    int n = t / K, k = t % K;
    out[t] = (f16)in[(size_t)n * ld + off + k];
}

// ---------- layer1: H1 = relu(bn(x @ W1^T + b1)) in fp16, fused ----------
__global__ void layer1_kernel(const float* __restrict__ X, const float* __restrict__ W1,
                              const float* __restrict__ b1, const float* __restrict__ g1,
                              const float* __restrict__ be1, const float* __restrict__ m1,
                              const float* __restrict__ v1, f16* __restrict__ H1, int M) {
    __shared__ float w[384], bb[128], sg[128], sb[128], sm[128], sv[128];
    for (int i = threadIdx.x; i < 384; i += 256) w[i] = W1[i];
    if (threadIdx.x < 128) {
        int c = threadIdx.x;
        bb[c] = b1[c]; sg[c] = g1[c]; sb[c] = be1[c]; sm[c] = m1[c]; sv[c] = v1[c];
    }
    __syncthreads();
    int t = blockIdx.x * 256 + threadIdx.x;
    if (t >= M * 16) return;
    int row = t >> 4, cg = (t & 15) * 8;
    float x0 = X[(size_t)row * 3], x1 = X[(size_t)row * 3 + 1], x2 = X[(size_t)row * 3 + 2];
    f16x8 outv;
#pragma unroll
    for (int j = 0; j < 8; ++j) {
        int c = cg + j;
        float tv = x0 * w[c * 3] + x1 * w[c * 3 + 1] + x2 * w[c * 3 + 2] + bb[c];
        float vv = (tv - sm[c]) * rsqrtf(sv[c] + 1e-5f) * sg[c] + sb[c];
        outv[j] = (f16)fmaxf(vv, 0.f);
    }
    *(f16x8*)&H1[(size_t)row * 128 + cg] = outv;
}

// ---------- MFMA GEMM ----------
__global__ __launch_bounds__(256) void mfma_gemm_kernel(
        const f16* __restrict__ A, const f16* __restrict__ W, int K, int N,
        const float* __restrict__ bias, const float* __restrict__ bias2d,
        const float* __restrict__ bng, const float* __restrict__ bnb,
        const float* __restrict__ bnm, const float* __restrict__ bnv,
        f16* __restrict__ Cout, unsigned* __restrict__ maxkey,
        int rows_per_batch, int relu) {
    __shared__ f16 Als[128 * 40];
    __shared__ f16 Bls[128 * 40];
    int tid = threadIdx.x;
    int lane = tid & 63;
    int wave = tid >> 6;
    int wm = wave & 1, wn = wave >> 1;
    int c16 = lane & 15, quad = lane >> 4;
    int row0 = blockIdx.y * 128, col0 = blockIdx.x * 128;
    int sr = tid >> 2;
    int skc = (tid & 3) * 8;

    f32x4 acc[4][4];
#pragma unroll
    for (int i = 0; i < 4; ++i)
#pragma unroll
        for (int j = 0; j < 4; ++j) acc[i][j] = (f32x4){0.f, 0.f, 0.f, 0.f};

    for (int k0 = 0; k0 < K; k0 += 32) {
#pragma unroll
        for (int i = 0; i < 2; ++i) {
            int r2 = sr + i * 64;
            f16x8 av = *(const f16x8*)(A + (size_t)(row0 + r2) * K + k0 + skc);
            *(f16x8*)&Als[r2 * 40 + skc] = av;
            f16x8 bv = *(const f16x8*)(W + (size_t)(col0 + r2) * K + k0 + skc);
            *(f16x8*)&Bls[r2 * 40 + skc] = bv;
        }
        __syncthreads();
        f16x8 af[4], bf[4];
#pragma unroll
        for (int s = 0; s < 4; ++s) {
            af[s] = *(const f16x8*)&Als[(wm * 64 + s * 16 + c16) * 40 + quad * 8];
            bf[s] = *(const f16x8*)&Bls[(wn * 64 + s * 16 + c16) * 40 + quad * 8];
        }
#pragma unroll
        for (int ms = 0; ms < 4; ++ms)
#pragma unroll
            for (int ns = 0; ns < 4; ++ns)
                acc[ms][ns] = __builtin_amdgcn_mfma_f32_16x16x32_f16(af[ms], bf[ns],
                                                                     acc[ms][ns], 0, 0, 0);
        __syncthreads();
    }

    int b = row0 / rows_per_batch;
#pragma unroll
    for (int ns = 0; ns < 4; ++ns) {
        int col = col0 + wn * 64 + ns * 16 + c16;
        float bv = bias ? bias[col] : 0.f;
        float b2v = bias2d ? bias2d[(size_t)b * N + col] : 0.f;
        float mx = -3e38f;
#pragma unroll
        for (int ms = 0; ms < 4; ++ms) {
#pragma unroll
            for (int j = 0; j < 4; ++j) {
                float v = acc[ms][ns][j] + bv + b2v;
                if (bng) v = (v - bnm[col]) * rsqrtf(bnv[col] + 1e-5f) * bng[col] + bnb[col];
                if (relu) v = fmaxf(v, 0.f);
                if (Cout)
                    Cout[(size_t)(row0 + wm * 64 + ms * 16 + quad * 4 + j) * N + col] = (f16)v;
                mx = fmaxf(mx, v);
            }
        }
        if (maxkey) {
            mx = fmaxf(mx, __shfl_xor(mx, 16, 64));
            mx = fmaxf(mx, __shfl_xor(mx, 32, 64));
            if (quad == 0) atomicMax(&maxkey[(size_t)b * N + col], fkey(mx));
        }
    }
}

// ---------- skinny GEMM v2: wave per column, coalesced float4 ----------
__global__ void skinny_v2_kernel(const float* __restrict__ A, const float* __restrict__ W,
                                 int ldw, int woff, const float* __restrict__ bias,
                                 float* __restrict__ C, int K, int N, int relu) {
    int wave = threadIdx.x >> 6, lane = threadIdx.x & 63;
    int col = blockIdx.x * 4 + wave;
    if (col >= N) return;
    const float* w = W + (size_t)col * ldw + woff;
    float acc[16];
#pragma unroll
    for (int m = 0; m < 16; ++m) acc[m] = 0.f;
    for (int k0 = 0; k0 < K; k0 += 256) {
        f32x4 wv = *(const f32x4*)(w + k0 + lane * 4);
#pragma unroll
        for (int m = 0; m < 16; ++m) {
            f32x4 av = *(const f32x4*)(A + (size_t)m * K + k0 + lane * 4);
            acc[m] += av[0] * wv[0] + av[1] * wv[1] + av[2] * wv[2] + av[3] * wv[3];
        }
    }
#pragma unroll
    for (int m = 0; m < 16; ++m)
#pragma unroll
        for (int s = 1; s < 64; s <<= 1) acc[m] += __shfl_xor(acc[m], s, 64);
    if (lane == 0) {
        float bv = bias[col];
#pragma unroll
        for (int m = 0; m < 16; ++m) {
            float v = acc[m] + bv;
            if (relu) v = fmaxf(v, 0.f);
            C[(size_t)m * N + col] = v;
        }
    }
}

__global__ void decode_kernel(const unsigned* __restrict__ k, float* __restrict__ f, int n) {
    int t = blockIdx.x * blockDim.x + threadIdx.x;
    if (t < n) f[t] = fkey_inv(k[t]);
}

// ---------- chamfer v2: 8 lanes per A-point, j-strided, shfl-min ----------
__global__ void chamfer_min_kernel(const float* __restrict__ A, int na,
                                   const float* __restrict__ Bp, int nb,
                                   float* __restrict__ slot) {
    int t = blockIdx.x * 256 + threadIdx.x;
    int pt = t >> 3, sl = t & 7;
    float val = 0.f;
    if (pt < BSZ * na) {
        int b = pt / na;
        const float* a = A + (size_t)pt * 3;
        float ax = a[0], ay = a[1], az = a[2];
        float aa = ax * ax + ay * ay + az * az;
        const float* Bb = Bp + (size_t)b * nb * 3;
        float m = 3e38f;
        for (int j = sl; j < nb; j += 8) {
            float bx = Bb[j * 3 + 0], by = Bb[j * 3 + 1], bz = Bb[j * 3 + 2];
            float d = aa + bx * bx + by * by + bz * bz - 2.0f * (ax * bx + ay * by + az * bz);
            m = fminf(m, d);
        }
#pragma unroll
        for (int s = 1; s < 8; s <<= 1) m = fminf(m, __shfl_xor(m, s, 64));
        if (sl == 0) val = sqrtf(fmaxf(m, 1e-12f));
    }
    __shared__ float sdata[256];
    sdata[threadIdx.x] = val;
    __syncthreads();
    for (int s = 128; s > 0; s >>= 1) {
        if (threadIdx.x < s) sdata[threadIdx.x] += sdata[threadIdx.x + s];
        __syncthreads();
    }
    if (threadIdx.x == 0) atomicAdd(slot, sdata[0]);
}

// ---------- smooth-L1 latent loss sum ----------
__global__ void latent_kernel(const float* __restrict__ f1, const float* __restrict__ f2,
                              int n, float* __restrict__ slot) {
    int t = blockIdx.x * blockDim.x + threadIdx.x;
    float val = 0.f;
    if (t < n) {
        float d = f1[t] - f2[t];
        float ad = fabsf(d);
        val = (ad < 1.f) ? (0.5f * d * d) : (ad - 0.5f);
    }
    __shared__ float sdata[256];
    sdata[threadIdx.x] = val;
    __syncthreads();
    for (int s = 128; s > 0; s >>= 1) {
        if (threadIdx.x < s) sdata[threadIdx.x] += sdata[threadIdx.x + s];
        __syncthreads();
    }
    if (threadIdx.x == 0) atomicAdd(slot, sdata[0]);
}

// ---------- 3x3 symmetric smallest eigenvector (double, analytic) ----------
__device__ void smallest_evec(double cxx, double cxy, double cxz,
                              double cyy, double cyz, double czz, double ev[3]) {
    double p1 = cxy * cxy + cxz * cxz + cyz * cyz;
    double q = (cxx + cyy + czz) / 3.0;
    double p2 = (cxx - q) * (cxx - q) + (cyy - q) * (cyy - q) + (czz - q) * (czz - q) + 2.0 * p1;
    double lam = q;
    if (p2 > 0.0) {
        double p = sqrt(p2 / 6.0);
        double b00 = (cxx - q) / p, b11 = (cyy - q) / p, b22 = (czz - q) / p;
        double b01 = cxy / p, b02 = cxz / p, b12 = cyz / p;
        double detB = b00 * (b11 * b22 - b12 * b12) - b01 * (b01 * b22 - b12 * b02)
                    + b02 * (b01 * b12 - b11 * b02);
        double r = detB * 0.5;
        r = r < -1.0 ? -1.0 : (r > 1.0 ? 1.0 : r);
        double phi = acos(r) / 3.0;
        lam = q + 2.0 * p * cos(phi + 2.0943951023931953);
    }
    double r0x = cxx - lam, r0y = cxy, r0z = cxz;
    double r1x = cxy, r1y = cyy - lam, r1z = cyz;
    double r2x = cxz, r2y = cyz, r2z = czz - lam;
    double c0x = r0y * r1z - r0z * r1y, c0y = r0z * r1x - r0x * r1z, c0z = r0x * r1y - r0y * r1x;
    double c1x = r0y * r2z - r0z * r2y, c1y = r0z * r2x - r0x * r2z, c1z = r0x * r2y - r0y * r2x;
    double c2x = r1y * r2z - r1z * r2y, c2y = r1z * r2x - r1x * r2z, c2z = r1x * r2y - r1y * r2x;
    double n0 = c0x * c0x + c0y * c0y + c0z * c0z;
    double n1 = c1x * c1x + c1y * c1y + c1z * c1z;
    double n2 = c2x * c2x + c2y * c2y + c2z * c2z;
    double bx = c0x, by = c0y, bz = c0z, bn = n0;
    if (n1 > bn) { bx = c1x; by = c1y; bz = c1z; bn = n1; }
    if (n2 > bn) { bx = c2x; by = c2y; bz = c2z; bn = n2; }
    if (bn < 1e-280) { ev[0] = 1.0; ev[1] = 0.0; ev[2] = 0.0; return; }
    double inv = 1.0 / sqrt(bn);
    ev[0] = bx * inv; ev[1] = by * inv; ev[2] = bz * inv;
}

// ---------- normals ----------
__global__ void normals_kernel(const float* __restrict__ pred, const int* __restrict__ knn,
                               float* __restrict__ nrm) {
    int t = blockIdx.x * blockDim.x + threadIdx.x;
    if (t >= BSZ * NPTS) return;
    int b = t / NPTS, i = t % NPTS;
    const float* P = pred + (size_t)b * NPTS * 3;
    const int* id = knn + (size_t)t * 32;
    float px[32], py[32], pz[32];
    double sx = 0, sy = 0, sz = 0;
    for (int k = 0; k < 32; ++k) {
        int j = id[k];
        px[k] = P[j * 3 + 0]; py[k] = P[j * 3 + 1]; pz[k] = P[j * 3 + 2];
        sx += px[k]; sy += py[k]; sz += pz[k];
    }
    double mx = sx / 32.0, my = sy / 32.0, mz = sz / 32.0;
    double cxx = 0, cxy = 0, cxz = 0, cyy = 0, cyz = 0, czz = 0;
    for (int k = 0; k < 32; ++k) {
        double dx = px[k] - mx, dy = py[k] - my, dz = pz[k] - mz;
        cxx += dx * dx; cxy += dx * dy; cxz += dx * dz;
        cyy += dy * dy; cyz += dy * dz; czz += dz * dz;
    }
    cxx /= 32.0; cxy /= 32.0; cxz /= 32.0; cyy /= 32.0; cyz /= 32.0; czz /= 32.0;
    double ev[3];
    smallest_evec(cxx, cxy, cxz, cyy, cyz, czz, ev);
    float qx = P[i * 3 + 0], qy = P[i * 3 + 1], qz = P[i * 3 + 2];
    double proj = 0.0;
    for (int k = 0; k < 32; ++k)
        proj += (px[k] - qx) * ev[0] + (py[k] - qy) * ev[1] + (pz[k] - qz) * ev[2];
    double s = (proj >= 0.0) ? 1.0 : -1.0;
    nrm[(size_t)t * 3 + 0] = (float)(ev[0] * s);
    nrm[(size_t)t * 3 + 1] = (float)(ev[1] * s);
    nrm[(size_t)t * 3 + 2] = (float)(ev[2] * s);
}

// ---------- manifold loss: reads first 8 of the 32-NN list ----------
__global__ void manifold_kernel(const float* __restrict__ nrm, const int* __restrict__ knn,
                                int kstride, float* __restrict__ slot) {
    int t = blockIdx.x * blockDim.x + threadIdx.x;
    float val = 0.f;
    if (t < BSZ * NPTS) {
        int b = t / NPTS;
        const float* NB = nrm + (size_t)b * NPTS * 3;
        const int* id = knn + (size_t)t * kstride;
        int j0 = id[0];
        float ax = NB[j0 * 3 + 0], ay = NB[j0 * 3 + 1], az = NB[j0 * 3 + 2];
        float an = fmaxf(sqrtf(ax * ax + ay * ay + az * az), 1e-6f);
        float x[8]; float s = 0.f;
        for (int k = 0; k < 8; ++k) {
            int j = id[k];
            float bx = NB[j * 3 + 0], by = NB[j * 3 + 1], bz = NB[j * 3 + 2];
            float bn_ = fmaxf(sqrtf(bx * bx + by * by + bz * bz), 1e-6f);
            float c = (ax * bx + ay * by + az * bz) / (an * bn_);
            x[k] = 1.f - c; s += x[k];
        }
        float mean = s / 8.f;
        float var = 0.f;
        for (int k = 0; k < 8; ++k) { float d = x[k] - mean; var += d * d; }
        val = sqrtf(var / 7.f);
    }
    __shared__ float sdata[256];
    sdata[threadIdx.x] = val;
    __syncthreads();
    for (int s2 = 128; s2 > 0; s2 >>= 1) {
        if (threadIdx.x < s2) sdata[threadIdx.x] += sdata[threadIdx.x + s2];
        __syncthreads();
    }
    if (threadIdx.x == 0) atomicAdd(slot, sdata[0]);
}

__global__ void finalize_kernel(const float* __restrict__ acc, float* __restrict__ out) {
    float l_recon = 0.5f * (acc[0] / (16.f * 2048.f) + acc[1] / (16.f * 2432.f));
    float l_match = 0.5f * (acc[2] / (16.f * 1024.f) + acc[3] / (16.f * 1216.f));
    float l_latent = acc[4] / (16.f * 1024.f);
    float l_man = 0.1f * (acc[5] / (16.f * 2048.f));
    out[0] = l_recon + l_match + l_latent + l_man;
    out[1] = l_recon;
    out[2] = l_match;
    out[3] = l_latent;
    out[4] = l_man;
}

// ================= host =================
extern "C" void kernel_launch(void* const* d_in, const int* in_sizes, int n_in,
                              void* d_out, int out_size, void* d_ws, size_t ws_size,
                              hipStream_t stream) {
    (void)in_sizes; (void)n_in; (void)out_size; (void)ws_size;
    const float* pts = (const float*)d_in[0];
    const float* W1 = (const float*)d_in[1];
    const float* b1 = (const float*)d_in[2];
    const float* g1 = (const float*)d_in[3];
    const float* be1 = (const float*)d_in[4];
    const float* m1 = (const float*)d_in[5];
    const float* v1 = (const float*)d_in[6];
    const float* W2 = (const float*)d_in[7];
    const float* b2 = (const float*)d_in[8];
    const float* W3 = (const float*)d_in[9];
    const float* b3 = (const float*)d_in[10];
    const float* g2 = (const float*)d_in[11];
    const float* be2 = (const float*)d_in[12];
    const float* m2 = (const float*)d_in[13];
    const float* v2 = (const float*)d_in[14];
    const float* W4 = (const float*)d_in[15];
    const float* b4 = (const float*)d_in[16];
    const float* D1W = (const float*)d_in[17];
    const float* D1b = (const float*)d_in[18];
    const float* D2W = (const float*)d_in[19];
    const float* D2b = (const float*)d_in[20];
    const float* D3W = (const float*)d_in[21];
    const float* D3b = (const float*)d_in[22];
    const float* D4W = (const float*)d_in[23];
    const float* D4b = (const float*)d_in[24];

    char* ws = (char*)d_ws;
    size_t off = 0;
    auto alloc = [&](size_t bytes) -> void* {
        void* p = ws + off;
        off += (bytes + 255) & ~(size_t)255;
        return p;
    };
    float* center   = (float*)alloc((size_t)BSZ * NG * 3 * 4);
    int*   knnc     = (int*)  alloc((size_t)BSZ * NG * GS * 4);
    float* rebuild0 = (float*)alloc((size_t)BSZ * 2048 * 3 * 4);
    float* rebuild1 = (float*)alloc((size_t)BSZ * 1024 * 3 * 4);
    f16*   W2h      = (f16*)  alloc((size_t)256 * 128 * 2);
    f16*   W3h      = (f16*)  alloc((size_t)512 * 256 * 2);
    f16*   W4h      = (f16*)  alloc((size_t)1024 * 512 * 2);
    f16*   H1h      = (f16*)  alloc((size_t)BSZ * 2048 * 128 * 2);
    f16*   H2h      = (f16*)  alloc((size_t)BSZ * 2048 * 256 * 2);
    f16*   H3h      = (f16*)  alloc((size_t)BSZ * 2048 * 512 * 2);
    unsigned* gmaxkey = (unsigned*)alloc((size_t)BSZ * 256 * 4);
    float* gmaxb    = (float*)alloc((size_t)BSZ * 256 * 4);
    float* gpart    = (float*)alloc((size_t)BSZ * 512 * 4);
    unsigned* featkey = (unsigned*)alloc((size_t)BSZ * 1024 * 4);
    float* feat     = (float*)alloc((size_t)BSZ * 1024 * 4);
    float* featrec  = (float*)alloc((size_t)BSZ * 1024 * 4);
    float* dh1      = (float*)alloc((size_t)BSZ * 2048 * 4);
    float* dh2      = (float*)alloc((size_t)BSZ * 2048 * 4);
    float* dh3      = (float*)alloc((size_t)BSZ * 2048 * 4);
    float* pred     = (float*)alloc((size_t)BSZ * 6144 * 4);
    int*   idxa     = (int*)  alloc((size_t)BSZ * 64 * NBRK * 4);
    float* gatha    = (float*)alloc((size_t)BSZ * 64 * NBRK * 3 * 4);
    int*   idxb     = (int*)  alloc((size_t)BSZ * 32 * NBRK * 4);
    float* gathb    = (float*)alloc((size_t)BSZ * 32 * NBRK * 3 * 4);
    int*   idxc     = (int*)  alloc((size_t)BSZ * 32 * 32 * 4);
    float* gathc    = (float*)alloc((size_t)BSZ * 1024 * 3 * 4);
    int*   knn32    = (int*)  alloc((size_t)BSZ * 2048 * 32 * 4);
    float* nrmbuf   = (float*)alloc((size_t)BSZ * 2048 * 3 * 4);
    float* accum    = (float*)alloc(8 * 4);

    hipMemsetAsync(accum, 0, 8 * 4, stream);

    cvt_w_kernel<<<(256 * 128 + 255) / 256, 256, 0, stream>>>(W2, 128, 0, 128, W2h, 256 * 128);
    cvt_w_kernel<<<(512 * 256 + 255) / 256, 256, 0, stream>>>(W3, 512, 256, 256, W3h, 512 * 256);
    cvt_w_kernel<<<(1024 * 512 + 255) / 256, 256, 0, stream>>>(W4, 512, 0, 512, W4h, 1024 * 512);

    auto knn = [&](const float* Q, int q_bstride, int q_off, int nq,
                   const float* DB, int k, int* out) {
        int total = BSZ * nq;
        knn_kernel_v8<<<(total + 3) / 4, 256, 0, stream>>>(Q, q_bstride, q_off, nq,
                                                           DB, k, out, BSZ);
    };

    // FPS + grouping
    fps_kernel_v4<<<BSZ, 256, 0, stream>>>(pts, center);
    knn(center, NG, 0, NG, pts, GS, knnc);
    gather_points_kernel<<<(BSZ * 2048 + 255) / 256, 256, 0, stream>>>(pts, NPTS, knnc, NG * GS,
                                                                       0, 2048, rebuild0, BSZ);
    gather_points_kernel<<<(BSZ * 1024 + 255) / 256, 256, 0, stream>>>(pts, NPTS, knnc, NG * GS,
                                                                       2048, 1024, rebuild1, BSZ);

    auto enc = [&](const float* X, int n, float* featout) {
        int M = BSZ * n;
        layer1_kernel<<<M / 16, 256, 0, stream>>>(X, W1, b1, g1, be1, m1, v1, H1h, M);
        hipMemsetAsync(gmaxkey, 0, (size_t)BSZ * 256 * 4, stream);
        mfma_gemm_kernel<<<dim3(256 / 128, M / 128), 256, 0, stream>>>(
            H1h, W2h, 128, 256, b2, nullptr, nullptr, nullptr, nullptr, nullptr,
            H2h, gmaxkey, n, 0);
        decode_kernel<<<(BSZ * 256 + 255) / 256, 256, 0, stream>>>(gmaxkey, gmaxb, BSZ * 256);
        skinny_v2_kernel<<<(512 + 3) / 4, 256, 0, stream>>>(gmaxb, W3, 512, 0, b3,
                                                            gpart, 256, 512, 0);
        mfma_gemm_kernel<<<dim3(512 / 128, M / 128), 256, 0, stream>>>(
            H2h, W3h, 256, 512, nullptr, gpart, g2, be2, m2, v2, H3h, nullptr, n, 1);
        hipMemsetAsync(featkey, 0, (size_t)BSZ * 1024 * 4, stream);
        mfma_gemm_kernel<<<dim3(1024 / 128, M / 128), 256, 0, stream>>>(
            H3h, W4h, 512, 1024, b4, nullptr, nullptr, nullptr, nullptr, nullptr,
            nullptr, featkey, n, 0);
        decode_kernel<<<(BSZ * 1024 + 255) / 256, 256, 0, stream>>>(featkey, featout, BSZ * 1024);
    };

    enc(rebuild0, 2048, feat);

    // decoder (skinny M=16, fp32, coalesced)
    skinny_v2_kernel<<<2048 / 4, 256, 0, stream>>>(feat, D1W, 1024, 0, D1b, dh1, 1024, 2048, 1);
    skinny_v2_kernel<<<2048 / 4, 256, 0, stream>>>(dh1, D2W, 2048, 0, D2b, dh2, 2048, 2048, 1);
    skinny_v2_kernel<<<2048 / 4, 256, 0, stream>>>(dh2, D3W, 2048, 0, D3b, dh3, 2048, 2048, 1);
    skinny_v2_kernel<<<6144 / 4, 256, 0, stream>>>(dh3, D4W, 2048, 0, D4b, pred, 2048, 6144, 0);

    // l_recon
    knn(center, NG, 0, 64, pred, NBRK, idxa);
    gather_points_kernel<<<(BSZ * 2432 + 255) / 256, 256, 0, stream>>>(pred, 2048, idxa, 64 * NBRK,
                                                                       0, 2432, gatha, BSZ);
    chamfer_min_kernel<<<(BSZ * 2048 * 8 + 255) / 256, 256, 0, stream>>>(rebuild0, 2048,
                                                                         gatha, 2432, accum + 0);
    chamfer_min_kernel<<<(BSZ * 2432 * 8 + 255) / 256, 256, 0, stream>>>(gatha, 2432,
                                                                         rebuild0, 2048, accum + 1);
    // l_match
    knn(center, NG, 64, 32, pred, NBRK, idxb);
    gather_points_kernel<<<(BSZ * 1216 + 255) / 256, 256, 0, stream>>>(pred, 2048, idxb, 32 * NBRK,
                                                                       0, 1216, gathb, BSZ);
    chamfer_min_kernel<<<(BSZ * 1024 * 8 + 255) / 256, 256, 0, stream>>>(rebuild1, 1024,
                                                                         gathb, 1216, accum + 2);
    chamfer_min_kernel<<<(BSZ * 1216 * 8 + 255) / 256, 256, 0, stream>>>(gathb, 1216,
                                                                         rebuild1, 1024, accum + 3);
    // l_latent
    knn(center, NG, 96, 32, pred, 32, idxc);
    gather_points_kernel<<<(BSZ * 1024 + 255) / 256, 256, 0, stream>>>(pred, 2048, idxc, 32 * 32,
                                                                       0, 1024, gathc, BSZ);
    enc(gathc, 1024, featrec);
    latent_kernel<<<(BSZ * 1024 + 255) / 256, 256, 0, stream>>>(feat, featrec, BSZ * 1024,
                                                                accum + 4);
    // l_man: one self-KNN (k=32); manifold uses first 8 (stable top-k prefix)
    knn(pred, 2048, 0, 2048, pred, 32, knn32);
    normals_kernel<<<(BSZ * 2048 + 255) / 256, 256, 0, stream>>>(pred, knn32, nrmbuf);
    manifold_kernel<<<(BSZ * 2048 + 255) / 256, 256, 0, stream>>>(nrmbuf, knn32, 32, accum + 5);

    finalize_kernel<<<1, 1, 0, stream>>>(accum, (float*)d_out);
}